// Round 4
// baseline (1321.040 us; speedup 1.0000x reference)
//
#include <hip/hip_runtime.h>
#include <hip/hip_cooperative_groups.h>
#include <math.h>

namespace cg = cooperative_groups;

#define T_TOK 16384
#define D_DIM 2048
#define NSLOT 64
#define H_DIM 1024
#define KSPLIT 4
#define KCH 512          // D_DIM / KSPLIT
#define NBLK 256

// ---------------------------------------------------------------------------
// Cooperative front half: logits -> stats -> comb -> slot_in. Grid 256x256.
// LDS union <= 40.5 KB so even 64KB-based co-residency math admits 1 block/CU.
// ---------------------------------------------------------------------------
__global__ __launch_bounds__(256, 2) void k_front(
    const float* __restrict__ x, const float* __restrict__ Wd,
    float* __restrict__ wsp)
{
    cg::grid_group grid = cg::this_grid();
    const int tid = threadIdx.x;
    const int bid = blockIdx.x;

    float* plog     = wsp;                                    // 4*16384*64
    float* logits   = plog + (size_t)KSPLIT * T_TOK * NSLOT;  // 16384*64
    float* comb     = logits + (size_t)T_TOK * NSLOT;         // 16384*64
    float* pm       = comb + (size_t)T_TOK * NSLOT;           // 256*64
    float* pz       = pm + (size_t)NBLK * NSLOT;              // 256*64
    float* mS       = pz + (size_t)NBLK * NSLOT;              // 64
    float* invZ     = mS + NSLOT;                             // 64
    float* partial  = invZ + NSLOT;                           // 32*64*2048
    float* slot_in  = partial + (size_t)32 * NSLOT * D_DIM;   // 64*2048

    __shared__ union {
        struct { float xs[256][32]; float wsb[64][32]; } p1;            // 40 KB
        struct { float ls[64][66]; } p2;                                // 16.5 KB
        struct { float lm[4][64]; float lz[4][64]; } p3;                // 2 KB
        struct { float xs[32][256]; float pls[32][64];
                 float msh[64]; float zsh[64]; } p4;                    // 40.5 KB
        struct { float4 red[256]; } p5;                                 // 4 KB
    } u;

    // ------------------------------------------------------------------ P1
    // partial logits: 64 token-blocks (256 tok) x 4 K-splits (KCH=512)
    {
        const int tb = bid >> 2, ks = bid & 3;
        const int tblk = tb * 256, koff = ks * KCH;
        const int tq = tid >> 3, sg = tid & 7;
        float acc[8][8] = {};
        for (int kc = 0; kc < KCH; kc += 32) {
            __syncthreads();
            #pragma unroll
            for (int ii = 0; ii < 8; ++ii) {
                int fi = tid + ii * 256; int t = fi >> 3, c = fi & 7;
                *(float4*)&u.p1.xs[t][(c ^ (t & 7)) << 2] =
                    *(const float4*)&x[(size_t)(tblk + t) * D_DIM + koff + kc + c * 4];
            }
            #pragma unroll
            for (int ii = 0; ii < 2; ++ii) {
                int fi = tid + ii * 256; int s = fi >> 3, c = fi & 7;
                *(float4*)&u.p1.wsb[s][(c ^ (s & 7)) << 2] =
                    *(const float4*)&Wd[(size_t)s * D_DIM + koff + kc + c * 4];
            }
            __syncthreads();
            #pragma unroll
            for (int c = 0; c < 8; ++c) {
                float4 wv[8];
                #pragma unroll
                for (int j = 0; j < 8; ++j)
                    wv[j] = *(const float4*)&u.p1.wsb[sg + 8 * j][(c ^ sg) << 2];
                #pragma unroll
                for (int i = 0; i < 8; ++i) {
                    float4 xv = *(const float4*)&u.p1.xs[tq + 32 * i][(c ^ (tq & 7)) << 2];
                    #pragma unroll
                    for (int j = 0; j < 8; ++j)
                        acc[i][j] += xv.x * wv[j].x + xv.y * wv[j].y +
                                     xv.z * wv[j].z + xv.w * wv[j].w;
                }
            }
        }
        #pragma unroll
        for (int i = 0; i < 8; ++i)
            #pragma unroll
            for (int j = 0; j < 8; ++j)
                plog[((size_t)ks * T_TOK + tblk + tq + 32 * i) * NSLOT + sg + 8 * j] =
                    acc[i][j];
    }
    grid.sync();

    // ------------------------------------------------------------------ P2
    // sum K-splits -> logits; row-softmax -> comb; per-64-token col stats
    {
        const int j0 = bid * 64;
        #pragma unroll
        for (int ii = 0; ii < 16; ++ii) {
            int fi = tid + ii * 256; int r = fi >> 6, s = fi & 63;
            float a = 0.f;
            #pragma unroll
            for (int ks = 0; ks < KSPLIT; ++ks)
                a += plog[((size_t)ks * T_TOK + j0 + r) * NSLOT + s];
            logits[(size_t)(j0 + r) * NSLOT + s] = a;
            u.p2.ls[r][s] = a;
        }
        __syncthreads();
        if (tid < 64) {               // column (dispatch) partial stats
            float m = -1e30f, z = 0.f;
            for (int r = 0; r < 64; ++r) {
                float v = u.p2.ls[r][tid];
                float nm = fmaxf(m, v);
                z = z * __expf(m - nm) + __expf(v - nm);
                m = nm;
            }
            pm[(size_t)bid * NSLOT + tid] = m;
            pz[(size_t)bid * NSLOT + tid] = z;
        } else if (tid < 128) {       // row softmax -> comb (wave 1, 64 rows)
            const int r = tid - 64;
            float M = -1e30f;
            for (int s = 0; s < 64; ++s) M = fmaxf(M, u.p2.ls[r][s]);
            float Z = 0.f;
            for (int s = 0; s < 64; ++s) Z += __expf(u.p2.ls[r][s] - M);
            float rz = 1.f / Z;
            for (int s = 0; s < 64; ++s)
                comb[(size_t)(j0 + r) * NSLOT + s] = __expf(u.p2.ls[r][s] - M) * rz;
        }
    }
    grid.sync();

    // ------------------------------------------------------------------ P3
    if (bid == 0) {
        const int part = tid >> 6, s = tid & 63;
        float m = -1e30f, z = 0.f;
        for (int c = part * 64; c < part * 64 + 64; ++c) {
            float m2 = pm[(size_t)c * NSLOT + s], z2 = pz[(size_t)c * NSLOT + s];
            float nm = fmaxf(m, m2);
            z = z * __expf(m - nm) + z2 * __expf(m2 - nm);
            m = nm;
        }
        u.p3.lm[part][s] = m; u.p3.lz[part][s] = z;
        __syncthreads();
        if (tid < 64) {
            float M = u.p3.lm[0][tid], Z = u.p3.lz[0][tid];
            #pragma unroll
            for (int p = 1; p < 4; ++p) {
                float m2 = u.p3.lm[p][tid], z2 = u.p3.lz[p][tid];
                float nm = fmaxf(M, m2);
                Z = Z * __expf(M - nm) + z2 * __expf(m2 - nm);
                M = nm;
            }
            mS[tid] = M; invZ[tid] = 1.f / Z;
        }
    }
    grid.sync();

    // ------------------------------------------------------------------ P4
    // slot_input partials: 8 d-tiles (256) x 32 t-chunks (512 tok)
    {
        const int dt = bid & 7, tc = bid >> 3;
        const int d0 = dt * 256, tc0 = tc * 512;
        if (tid < 64) { u.p4.msh[tid] = mS[tid]; u.p4.zsh[tid] = invZ[tid]; }
        const int dg = tid & 31, sgq = tid >> 5;
        float4 acc0[8] = {}, acc1[8] = {};
        for (int sub = 0; sub < 16; ++sub) {
            const int t0 = tc0 + sub * 32;
            __syncthreads();
            #pragma unroll
            for (int ii = 0; ii < 8; ++ii) {
                int fi = tid + ii * 256; int r = fi >> 6, c4 = fi & 63;
                *(float4*)&u.p4.xs[r][c4 * 4] =
                    *(const float4*)&x[(size_t)(t0 + r) * D_DIM + d0 + c4 * 4];
            }
            #pragma unroll
            for (int ii = 0; ii < 8; ++ii) {
                int fi = tid + ii * 256; int r = fi >> 6, s = fi & 63;
                u.p4.pls[r][s] =
                    __expf(logits[(size_t)(t0 + r) * NSLOT + s] - u.p4.msh[s]) * u.p4.zsh[s];
            }
            __syncthreads();
            for (int t = 0; t < 32; ++t) {
                float4 xv0 = *(const float4*)&u.p4.xs[t][dg * 4];
                float4 xv1 = *(const float4*)&u.p4.xs[t][128 + dg * 4];
                #pragma unroll
                for (int i = 0; i < 8; ++i) {
                    float p = u.p4.pls[t][sgq * 8 + i];
                    acc0[i].x += p * xv0.x; acc0[i].y += p * xv0.y;
                    acc0[i].z += p * xv0.z; acc0[i].w += p * xv0.w;
                    acc1[i].x += p * xv1.x; acc1[i].y += p * xv1.y;
                    acc1[i].z += p * xv1.z; acc1[i].w += p * xv1.w;
                }
            }
        }
        #pragma unroll
        for (int i = 0; i < 8; ++i) {
            int s = sgq * 8 + i;
            *(float4*)&partial[((size_t)tc * NSLOT + s) * D_DIM + d0 + dg * 4] = acc0[i];
            *(float4*)&partial[((size_t)tc * NSLOT + s) * D_DIM + d0 + 128 + dg * 4] = acc1[i];
        }
    }
    grid.sync();

    // ------------------------------------------------------------------ P5
    // reduce 32 t-chunks -> slot_in (64x2048 = 32768 float4)
    {
        const float4* partial4 = (const float4*)partial;
        float4* slot_in4 = (float4*)slot_in;
        const int o = bid * 128 + (tid & 127);
        const int part = tid >> 7;   // 0..1
        float4 a = {0.f, 0.f, 0.f, 0.f};
        for (int c = part * 16; c < part * 16 + 16; ++c) {
            float4 v = partial4[(size_t)c * (NSLOT * D_DIM / 4) + o];
            a.x += v.x; a.y += v.y; a.z += v.z; a.w += v.w;
        }
        u.p5.red[tid] = a;
        __syncthreads();
        if (tid < 128) {
            float4 b = u.p5.red[tid];
            float4 v = u.p5.red[tid + 128];
            b.x += v.x; b.y += v.y; b.z += v.z; b.w += v.w;
            slot_in4[o] = b;
        }
    }
}

// ---------------------------------------------------------------------------
// MLP + combine: proven high-occupancy regular kernels (R1).
// ---------------------------------------------------------------------------
__global__ __launch_bounds__(256) void k_mlp1(const float* __restrict__ W1,
                                              const float* __restrict__ b1,
                                              const float* __restrict__ slot_in,
                                              float* __restrict__ h) {
    const int wave = threadIdx.x >> 6, lane = threadIdx.x & 63;
    const int row = blockIdx.x * 4 + wave;           // e*1024 + j
    const int e = row >> 10;
    const float* wr = W1 + (size_t)row * D_DIM;
    const float* xr = slot_in + (size_t)e * D_DIM;
    float acc = 0.f;
    #pragma unroll
    for (int i = 0; i < 8; ++i) {
        int k = (lane + i * 64) * 4;
        float4 w4 = *(const float4*)(wr + k);
        float4 x4 = *(const float4*)(xr + k);
        acc += w4.x * x4.x + w4.y * x4.y + w4.z * x4.z + w4.w * x4.w;
    }
    #pragma unroll
    for (int off = 32; off; off >>= 1) acc += __shfl_xor(acc, off);
    if (lane == 0) {
        float v = acc + b1[row];
        h[row] = 0.5f * v * (1.f + erff(v * 0.70710678118654752f));
    }
}

__global__ __launch_bounds__(256) void k_mlp2(const float* __restrict__ W2,
                                              const float* __restrict__ b2,
                                              const float* __restrict__ h,
                                              float* __restrict__ slot_out) {
    const int wave = threadIdx.x >> 6, lane = threadIdx.x & 63;
    const int row = blockIdx.x * 4 + wave;           // e*2048 + d
    const int e = row >> 11;
    const float* wr = W2 + (size_t)row * H_DIM;
    const float* xr = h + (size_t)e * H_DIM;
    float acc = 0.f;
    #pragma unroll
    for (int i = 0; i < 4; ++i) {
        int k = (lane + i * 64) * 4;
        float4 w4 = *(const float4*)(wr + k);
        float4 x4 = *(const float4*)(xr + k);
        acc += w4.x * x4.x + w4.y * x4.y + w4.z * x4.z + w4.w * x4.w;
    }
    #pragma unroll
    for (int off = 32; off; off >>= 1) acc += __shfl_xor(acc, off);
    if (lane == 0) slot_out[row] = acc + b2[row];
}

__global__ __launch_bounds__(256) void k_combine(const float* __restrict__ comb,
                                                 const float* __restrict__ so,
                                                 float* __restrict__ y) {
    __shared__ float cl[128][68];
    __shared__ float sol[64][128];
    const int tid = threadIdx.x;
    const int d0 = blockIdx.x * 128;
    const int tb = blockIdx.y * 128;
    const int tq = tid >> 4;    // 0..15
    const int dgq = tid & 15;   // 0..15
    #pragma unroll
    for (int ii = 0; ii < 8; ++ii) {
        int fi = tid + ii * 256;
        int r = fi >> 4, s4 = fi & 15;
        *(float4*)&cl[r][s4 * 4] =
            *(const float4*)&comb[(size_t)(tb + r) * NSLOT + s4 * 4];
    }
    #pragma unroll
    for (int ii = 0; ii < 8; ++ii) {
        int fi = tid + ii * 256;
        int r = fi >> 5, c4 = fi & 31;
        *(float4*)&sol[r][c4 * 4] =
            *(const float4*)&so[(size_t)r * D_DIM + d0 + c4 * 4];
    }
    __syncthreads();
    float4 acc0[8] = {}, acc1[8] = {};
    for (int s = 0; s < 64; ++s) {
        float4 sv0 = *(const float4*)&sol[s][dgq * 4];
        float4 sv1 = *(const float4*)&sol[s][64 + dgq * 4];
        #pragma unroll
        for (int i = 0; i < 8; ++i) {
            float cv = cl[tq + 16 * i][s];
            acc0[i].x += cv * sv0.x; acc0[i].y += cv * sv0.y;
            acc0[i].z += cv * sv0.z; acc0[i].w += cv * sv0.w;
            acc1[i].x += cv * sv1.x; acc1[i].y += cv * sv1.y;
            acc1[i].z += cv * sv1.z; acc1[i].w += cv * sv1.w;
        }
    }
    #pragma unroll
    for (int i = 0; i < 8; ++i) {
        *(float4*)&y[(size_t)(tb + tq + 16 * i) * D_DIM + d0 + dgq * 4] = acc0[i];
        *(float4*)&y[(size_t)(tb + tq + 16 * i) * D_DIM + d0 + 64 + dgq * 4] = acc1[i];
    }
}

// ---------------------------------------------------------------------------
extern "C" void kernel_launch(void* const* d_in, const int* in_sizes, int n_in,
                              void* d_out, int out_size, void* d_ws, size_t ws_size,
                              hipStream_t stream) {
    const float* x  = (const float*)d_in[0];
    const float* Wd = (const float*)d_in[1];
    const float* W1 = (const float*)d_in[2];
    const float* b1 = (const float*)d_in[3];
    const float* W2 = (const float*)d_in[4];
    const float* b2 = (const float*)d_in[5];
    float* y   = (float*)d_out;
    float* wsp = (float*)d_ws;

    // workspace layout (floats) — must match k_front
    float* plog     = wsp;
    float* logits   = plog + (size_t)KSPLIT * T_TOK * NSLOT;
    float* comb     = logits + (size_t)T_TOK * NSLOT;
    float* pm       = comb + (size_t)T_TOK * NSLOT;
    float* pz       = pm + (size_t)NBLK * NSLOT;
    float* mS       = pz + (size_t)NBLK * NSLOT;
    float* invZ     = mS + NSLOT;
    float* partial  = invZ + NSLOT;
    float* slot_in  = partial + (size_t)32 * NSLOT * D_DIM;
    float* h        = slot_in + (size_t)NSLOT * D_DIM;
    float* slot_out = h + (size_t)NSLOT * H_DIM;
    (void)logits; (void)pm; (void)pz; (void)mS; (void)invZ; (void)partial;

    void* args[] = {(void*)&x, (void*)&Wd, (void*)&wsp};
    hipLaunchCooperativeKernel((void*)k_front, dim3(NBLK), dim3(256), args, 0, stream);

    k_mlp1<<<(NSLOT * H_DIM) / 4, 256, 0, stream>>>(W1, b1, slot_in, h);
    k_mlp2<<<(NSLOT * D_DIM) / 4, 256, 0, stream>>>(W2, b2, h, slot_out);
    k_combine<<<dim3(16, 128), 256, 0, stream>>>(comb, slot_out, y);
}

// Round 5
// 470.168 us; speedup vs baseline: 2.8097x; 2.8097x over previous
//
#include <hip/hip_runtime.h>
#include <math.h>

#define T_TOK 16384
#define D_DIM 2048
#define NSLOT 64
#define H_DIM 1024
#define KSPLIT 8
#define KCH 256            // D_DIM / KSPLIT
#define TBLK 128           // tokens per logits block

// ---------------------------------------------------------------------------
// Kernel 1: partial logits. Block: 128 tok x 64 slots, 256 thr, 4x8 regtile
// (acc = 32 VGPR -> no spill). Grid (128 tb, 8 ksplit) = 1024 blocks.
// ---------------------------------------------------------------------------
__global__ __launch_bounds__(256) void k_logits(const float* __restrict__ x,
                                                const float* __restrict__ Wd,
                                                float* __restrict__ plog) {
    __shared__ float xs[128][32];
    __shared__ float ws[64][32];
    const int tid = threadIdx.x;
    const int tblk = blockIdx.x * TBLK;
    const int koff = blockIdx.y * KCH;
    const int tq = tid >> 3;     // 0..31
    const int sg = tid & 7;      // 0..7
    float acc[4][8] = {};

    for (int kc = 0; kc < KCH; kc += 32) {
        __syncthreads();
        #pragma unroll
        for (int ii = 0; ii < 4; ++ii) {          // xs: 1024 f4
            int fi = tid + ii * 256; int t = fi >> 3, c = fi & 7;
            *(float4*)&xs[t][(c ^ (t & 7)) << 2] =
                *(const float4*)&x[(size_t)(tblk + t) * D_DIM + koff + kc + c * 4];
        }
        #pragma unroll
        for (int ii = 0; ii < 2; ++ii) {          // ws: 512 f4
            int fi = tid + ii * 256; int s = fi >> 3, c = fi & 7;
            *(float4*)&ws[s][(c ^ (s & 7)) << 2] =
                *(const float4*)&Wd[(size_t)s * D_DIM + koff + kc + c * 4];
        }
        __syncthreads();
        #pragma unroll
        for (int c = 0; c < 8; ++c) {
            float4 wv[8];
            #pragma unroll
            for (int j = 0; j < 8; ++j)
                wv[j] = *(const float4*)&ws[sg + 8 * j][(c ^ sg) << 2];
            #pragma unroll
            for (int i = 0; i < 4; ++i) {
                float4 xv = *(const float4*)&xs[tq + 32 * i][(c ^ (tq & 7)) << 2];
                #pragma unroll
                for (int j = 0; j < 8; ++j)
                    acc[i][j] += xv.x * wv[j].x + xv.y * wv[j].y +
                                 xv.z * wv[j].z + xv.w * wv[j].w;
            }
        }
    }
    const size_t ksbase = (size_t)blockIdx.y * T_TOK;
    #pragma unroll
    for (int i = 0; i < 4; ++i)
        #pragma unroll
        for (int j = 0; j < 8; ++j)
            plog[(ksbase + tblk + tq + 32 * i) * NSLOT + sg + 8 * j] = acc[i][j];
}

// ---------------------------------------------------------------------------
// Kernel 2: sum K-splits -> E = exp(logits); per-block column sums of E.
// grid 64 (256 tokens each), block 256.
// ---------------------------------------------------------------------------
__global__ __launch_bounds__(256) void k_lsum(const float* __restrict__ plog,
                                              float* __restrict__ elog,
                                              float* __restrict__ pz) {
    __shared__ float zsh[4][64];
    const int tid = threadIdx.x;
    const int s = tid & 63, rq = tid >> 6;
    const int j0 = blockIdx.x * 256;
    float zacc = 0.f;
    for (int i = 0; i < 64; ++i) {
        int r = j0 + rq * 64 + i;
        float v = 0.f;
        #pragma unroll
        for (int ks = 0; ks < KSPLIT; ++ks)
            v += plog[((size_t)ks * T_TOK + r) * NSLOT + s];
        float e = __expf(v);
        elog[(size_t)r * NSLOT + s] = e;
        zacc += e;
    }
    zsh[rq][s] = zacc;
    __syncthreads();
    if (tid < 64)
        pz[(size_t)blockIdx.x * NSLOT + tid] =
            zsh[0][tid] + zsh[1][tid] + zsh[2][tid] + zsh[3][tid];
}

// Kernel 3: invZ[s] = 1 / sum_b pz[b][s]. 1 block, 64 threads.
__global__ void k_zred(const float* __restrict__ pz, float* __restrict__ invZ) {
    float z = 0.f;
    for (int b = 0; b < 64; ++b) z += pz[b * NSLOT + threadIdx.x];
    invZ[threadIdx.x] = 1.f / z;
}

// ---------------------------------------------------------------------------
// Kernel 4: unnormalized slot-input partials: partial[tc][s][d] =
// sum_{t in chunk} E[t][s] * x[t][d]. grid (8 d-tiles of 256, 64 t-chunks).
// ---------------------------------------------------------------------------
__global__ __launch_bounds__(256) void k_slot(const float* __restrict__ x,
        const float* __restrict__ elog, float* __restrict__ partial) {
    __shared__ float xs[32][256];
    __shared__ float pls[32][64];
    const int tid = threadIdx.x;
    const int d0 = blockIdx.x * 256;
    const int tc0 = blockIdx.y * 256;
    const int dg = tid & 31, sgq = tid >> 5;
    float4 acc0[8] = {}, acc1[8] = {};

    for (int sub = 0; sub < 8; ++sub) {
        const int t0 = tc0 + sub * 32;
        __syncthreads();
        #pragma unroll
        for (int ii = 0; ii < 8; ++ii) {
            int fi = tid + ii * 256; int r = fi >> 6, c4 = fi & 63;
            *(float4*)&xs[r][c4 * 4] =
                *(const float4*)&x[(size_t)(t0 + r) * D_DIM + d0 + c4 * 4];
        }
        #pragma unroll
        for (int ii = 0; ii < 2; ++ii) {
            int fi = tid + ii * 256; int r = fi >> 4, s4 = fi & 15;
            *(float4*)&pls[r][s4 * 4] =
                *(const float4*)&elog[(size_t)(t0 + r) * NSLOT + s4 * 4];
        }
        __syncthreads();
        for (int t = 0; t < 32; ++t) {
            float4 xv0 = *(const float4*)&xs[t][dg * 4];
            float4 xv1 = *(const float4*)&xs[t][128 + dg * 4];
            #pragma unroll
            for (int i = 0; i < 8; ++i) {
                float p = pls[t][sgq * 8 + i];
                acc0[i].x += p * xv0.x; acc0[i].y += p * xv0.y;
                acc0[i].z += p * xv0.z; acc0[i].w += p * xv0.w;
                acc1[i].x += p * xv1.x; acc1[i].y += p * xv1.y;
                acc1[i].z += p * xv1.z; acc1[i].w += p * xv1.w;
            }
        }
    }
    #pragma unroll
    for (int i = 0; i < 8; ++i) {
        int s = sgq * 8 + i;
        *(float4*)&partial[((size_t)blockIdx.y * NSLOT + s) * D_DIM + d0 + dg * 4] = acc0[i];
        *(float4*)&partial[((size_t)blockIdx.y * NSLOT + s) * D_DIM + d0 + 128 + dg * 4] = acc1[i];
    }
}

// Kernel 5: slot_in = invZ[s] * sum_c partial. grid 128, block 256.
__global__ __launch_bounds__(256) void k_sred(const float* __restrict__ partial,
                                              const float* __restrict__ invZ,
                                              float* __restrict__ slot_in) {
    const size_t idx = (size_t)blockIdx.x * 256 + threadIdx.x;   // float4 index
    const float iz = invZ[idx >> 9];                             // 512 f4 per slot
    float4 a = {0.f, 0.f, 0.f, 0.f};
    for (int c = 0; c < 64; ++c) {
        float4 v = ((const float4*)partial)[(size_t)c * (NSLOT * D_DIM / 4) + idx];
        a.x += v.x; a.y += v.y; a.z += v.z; a.w += v.w;
    }
    a.x *= iz; a.y *= iz; a.z *= iz; a.w *= iz;
    ((float4*)slot_in)[idx] = a;
}

// ---------------------------------------------------------------------------
// Kernel 6: h = gelu(W1 @ slot_in + b1). One wave per row, grid 16384.
// ---------------------------------------------------------------------------
__global__ __launch_bounds__(256) void k_mlp1(const float* __restrict__ W1,
                                              const float* __restrict__ b1,
                                              const float* __restrict__ slot_in,
                                              float* __restrict__ h) {
    const int wave = threadIdx.x >> 6, lane = threadIdx.x & 63;
    const int row = blockIdx.x * 4 + wave;           // e*1024 + j
    const int e = row >> 10;
    const float* wr = W1 + (size_t)row * D_DIM;
    const float* xr = slot_in + (size_t)e * D_DIM;
    float acc = 0.f;
    #pragma unroll
    for (int i = 0; i < 8; ++i) {
        int k = (lane + i * 64) * 4;
        float4 w4 = *(const float4*)(wr + k);
        float4 x4 = *(const float4*)(xr + k);
        acc += w4.x * x4.x + w4.y * x4.y + w4.z * x4.z + w4.w * x4.w;
    }
    #pragma unroll
    for (int off = 32; off; off >>= 1) acc += __shfl_xor(acc, off);
    if (lane == 0) {
        float v = acc + b1[row];
        h[row] = 0.5f * v * (1.f + erff(v * 0.70710678118654752f));
    }
}

// Kernel 7: slot_out = W2 @ h + b2. One wave per row, grid 32768.
__global__ __launch_bounds__(256) void k_mlp2(const float* __restrict__ W2,
                                              const float* __restrict__ b2,
                                              const float* __restrict__ h,
                                              float* __restrict__ slot_out) {
    const int wave = threadIdx.x >> 6, lane = threadIdx.x & 63;
    const int row = blockIdx.x * 4 + wave;           // e*2048 + d
    const int e = row >> 11;
    const float* wr = W2 + (size_t)row * H_DIM;
    const float* xr = h + (size_t)e * H_DIM;
    float acc = 0.f;
    #pragma unroll
    for (int i = 0; i < 4; ++i) {
        int k = (lane + i * 64) * 4;
        float4 w4 = *(const float4*)(wr + k);
        float4 x4 = *(const float4*)(xr + k);
        acc += w4.x * x4.x + w4.y * x4.y + w4.z * x4.z + w4.w * x4.w;
    }
    #pragma unroll
    for (int off = 32; off; off >>= 1) acc += __shfl_xor(acc, off);
    if (lane == 0) slot_out[row] = acc + b2[row];
}

// ---------------------------------------------------------------------------
// Kernel 8: y[t] = (sum_s E[t][s]*so[s]) * rinv_t. Block 128 tok x 128 d.
// Row-normalization folded into the accumulator epilogue. grid (16, 128).
// ---------------------------------------------------------------------------
__global__ __launch_bounds__(256) void k_combine(const float* __restrict__ elog,
                                                 const float* __restrict__ so,
                                                 float* __restrict__ y) {
    __shared__ float cl[128][68];
    __shared__ float sol[64][128];
    __shared__ float rinv[128];
    const int tid = threadIdx.x;
    const int d0 = blockIdx.x * 128;
    const int tb = blockIdx.y * 128;
    const int tq = tid >> 4;    // 0..15
    const int dgq = tid & 15;   // 0..15
    #pragma unroll
    for (int ii = 0; ii < 8; ++ii) {          // stage E: 128x64
        int fi = tid + ii * 256; int r = fi >> 4, s4 = fi & 15;
        *(float4*)&cl[r][s4 * 4] =
            *(const float4*)&elog[(size_t)(tb + r) * NSLOT + s4 * 4];
    }
    #pragma unroll
    for (int ii = 0; ii < 8; ++ii) {          // stage slot_out tile 64x128
        int fi = tid + ii * 256; int r = fi >> 5, c4 = fi & 31;
        *(float4*)&sol[r][c4 * 4] =
            *(const float4*)&so[(size_t)r * D_DIM + d0 + c4 * 4];
    }
    __syncthreads();
    if (tid < 128) {                          // row sums -> 1/Z_t
        float zs = 0.f;
        #pragma unroll
        for (int q = 0; q < 16; ++q) {
            float4 v = *(const float4*)&cl[tid][q * 4];
            zs += v.x + v.y + v.z + v.w;
        }
        rinv[tid] = 1.f / zs;
    }
    __syncthreads();
    float4 acc0[8] = {}, acc1[8] = {};
    for (int s = 0; s < 64; ++s) {
        float4 sv0 = *(const float4*)&sol[s][dgq * 4];
        float4 sv1 = *(const float4*)&sol[s][64 + dgq * 4];
        #pragma unroll
        for (int i = 0; i < 8; ++i) {
            float cv = cl[tq + 16 * i][s];
            acc0[i].x += cv * sv0.x; acc0[i].y += cv * sv0.y;
            acc0[i].z += cv * sv0.z; acc0[i].w += cv * sv0.w;
            acc1[i].x += cv * sv1.x; acc1[i].y += cv * sv1.y;
            acc1[i].z += cv * sv1.z; acc1[i].w += cv * sv1.w;
        }
    }
    #pragma unroll
    for (int i = 0; i < 8; ++i) {
        float rz = rinv[tq + 16 * i];
        acc0[i].x *= rz; acc0[i].y *= rz; acc0[i].z *= rz; acc0[i].w *= rz;
        acc1[i].x *= rz; acc1[i].y *= rz; acc1[i].z *= rz; acc1[i].w *= rz;
        *(float4*)&y[(size_t)(tb + tq + 16 * i) * D_DIM + d0 + dgq * 4] = acc0[i];
        *(float4*)&y[(size_t)(tb + tq + 16 * i) * D_DIM + d0 + 64 + dgq * 4] = acc1[i];
    }
}

// ---------------------------------------------------------------------------
extern "C" void kernel_launch(void* const* d_in, const int* in_sizes, int n_in,
                              void* d_out, int out_size, void* d_ws, size_t ws_size,
                              hipStream_t stream) {
    const float* x  = (const float*)d_in[0];
    const float* Wd = (const float*)d_in[1];
    const float* W1 = (const float*)d_in[2];
    const float* b1 = (const float*)d_in[3];
    const float* W2 = (const float*)d_in[4];
    const float* b2 = (const float*)d_in[5];
    float* y = (float*)d_out;

    float* w = (float*)d_ws;
    float* plog     = w;                                      // 8*16384*64
    float* elog     = plog + (size_t)KSPLIT * T_TOK * NSLOT;  // 16384*64
    float* pz       = elog + (size_t)T_TOK * NSLOT;           // 64*64
    float* invZ     = pz + 64 * NSLOT;                        // 64
    float* partial  = invZ + NSLOT;                           // 64*64*2048
    float* slot_in  = partial + (size_t)64 * NSLOT * D_DIM;   // 64*2048
    float* h        = slot_in + (size_t)NSLOT * D_DIM;        // 64*1024
    float* slot_out = h + (size_t)NSLOT * H_DIM;              // 64*2048

    k_logits<<<dim3(T_TOK / TBLK, KSPLIT), 256, 0, stream>>>(x, Wd, plog);
    k_lsum<<<64, 256, 0, stream>>>(plog, elog, pz);
    k_zred<<<1, 64, 0, stream>>>(pz, invZ);
    k_slot<<<dim3(8, 64), 256, 0, stream>>>(x, elog, partial);
    k_sred<<<128, 256, 0, stream>>>(partial, invZ, slot_in);
    k_mlp1<<<(NSLOT * H_DIM) / 4, 256, 0, stream>>>(W1, b1, slot_in, h);
    k_mlp2<<<(NSLOT * D_DIM) / 4, 256, 0, stream>>>(W2, b2, h, slot_out);
    k_combine<<<dim3(16, 128), 256, 0, stream>>>(elog, slot_out, y);
}

// Round 6
// 446.856 us; speedup vs baseline: 2.9563x; 1.0522x over previous
//
#include <hip/hip_runtime.h>
#include <math.h>

#define T_TOK 16384
#define D_DIM 2048
#define NSLOT 64
#define H_DIM 1024
#define KSPLIT 8
#define KCH 256            // D_DIM / KSPLIT
#define TBLK 128           // tokens per logits block

// ---------------------------------------------------------------------------
// Kernel 1: partial logits. Block: 128 tok x 64 slots, 256 thr, 4x8 regtile.
// Grid (128 tb, 8 ksplit). Block (0,0) also zeroes the pz4 atomic bins.
// ---------------------------------------------------------------------------
__global__ __launch_bounds__(256) void k_logits(const float* __restrict__ x,
                                                const float* __restrict__ Wd,
                                                float* __restrict__ plog,
                                                float* __restrict__ pz4) {
    __shared__ float xs[128][32];
    __shared__ float ws[64][32];
    const int tid = threadIdx.x;
    if (blockIdx.x == 0 && blockIdx.y == 0) pz4[tid] = 0.f;   // 256 bins
    const int tblk = blockIdx.x * TBLK;
    const int koff = blockIdx.y * KCH;
    const int tq = tid >> 3;     // 0..31
    const int sg = tid & 7;      // 0..7
    float acc[4][8] = {};

    for (int kc = 0; kc < KCH; kc += 32) {
        __syncthreads();
        #pragma unroll
        for (int ii = 0; ii < 4; ++ii) {          // xs: 1024 f4
            int fi = tid + ii * 256; int t = fi >> 3, c = fi & 7;
            *(float4*)&xs[t][(c ^ (t & 7)) << 2] =
                *(const float4*)&x[(size_t)(tblk + t) * D_DIM + koff + kc + c * 4];
        }
        #pragma unroll
        for (int ii = 0; ii < 2; ++ii) {          // ws: 512 f4
            int fi = tid + ii * 256; int s = fi >> 3, c = fi & 7;
            *(float4*)&ws[s][(c ^ (s & 7)) << 2] =
                *(const float4*)&Wd[(size_t)s * D_DIM + koff + kc + c * 4];
        }
        __syncthreads();
        #pragma unroll
        for (int c = 0; c < 8; ++c) {
            float4 wv[8];
            #pragma unroll
            for (int j = 0; j < 8; ++j)
                wv[j] = *(const float4*)&ws[sg + 8 * j][(c ^ sg) << 2];
            #pragma unroll
            for (int i = 0; i < 4; ++i) {
                float4 xv = *(const float4*)&xs[tq + 32 * i][(c ^ (tq & 7)) << 2];
                #pragma unroll
                for (int j = 0; j < 8; ++j)
                    acc[i][j] += xv.x * wv[j].x + xv.y * wv[j].y +
                                 xv.z * wv[j].z + xv.w * wv[j].w;
            }
        }
    }
    const size_t ksbase = (size_t)blockIdx.y * T_TOK;
    #pragma unroll
    for (int i = 0; i < 4; ++i)
        #pragma unroll
        for (int j = 0; j < 8; ++j)
            plog[(ksbase + tblk + tq + 32 * i) * NSLOT + sg + 8 * j] = acc[i][j];
}

// ---------------------------------------------------------------------------
// Kernel 2: sum K-splits -> E = exp(logits); column sums via atomic bins.
// grid 512 (32 tokens each), block 256 -> 2 waves/SIMD, 8-deep ILP.
// ---------------------------------------------------------------------------
__global__ __launch_bounds__(256) void k_lsum(const float* __restrict__ plog,
                                              float* __restrict__ elog,
                                              float* __restrict__ pz4) {
    __shared__ float zsh[4][64];
    const int tid = threadIdx.x;
    const int s = tid & 63, rq = tid >> 6;
    const int j0 = blockIdx.x * 32;
    float zacc = 0.f;
    #pragma unroll
    for (int i = 0; i < 8; ++i) {
        int r = j0 + rq * 8 + i;
        float v = 0.f;
        #pragma unroll
        for (int ks = 0; ks < KSPLIT; ++ks)
            v += plog[((size_t)ks * T_TOK + r) * NSLOT + s];
        float e = __expf(v);
        elog[(size_t)r * NSLOT + s] = e;
        zacc += e;
    }
    zsh[rq][s] = zacc;
    __syncthreads();
    if (tid < 64)
        atomicAdd(&pz4[(blockIdx.x & 3) * 64 + tid],
                  zsh[0][tid] + zsh[1][tid] + zsh[2][tid] + zsh[3][tid]);
}

// ---------------------------------------------------------------------------
// Kernel 3: unnormalized slot-input partials: partial[tc][s][d] =
// sum_{t in chunk} E[t][s] * x[t][d]. grid (8 d-tiles of 256, 64 t-chunks).
// ---------------------------------------------------------------------------
__global__ __launch_bounds__(256) void k_slot(const float* __restrict__ x,
        const float* __restrict__ elog, float* __restrict__ partial) {
    __shared__ float xs[32][256];
    __shared__ float pls[32][64];
    const int tid = threadIdx.x;
    const int d0 = blockIdx.x * 256;
    const int tc0 = blockIdx.y * 256;
    const int dg = tid & 31, sgq = tid >> 5;
    float4 acc0[8] = {}, acc1[8] = {};

    for (int sub = 0; sub < 8; ++sub) {
        const int t0 = tc0 + sub * 32;
        __syncthreads();
        #pragma unroll
        for (int ii = 0; ii < 8; ++ii) {
            int fi = tid + ii * 256; int r = fi >> 6, c4 = fi & 63;
            *(float4*)&xs[r][c4 * 4] =
                *(const float4*)&x[(size_t)(t0 + r) * D_DIM + d0 + c4 * 4];
        }
        #pragma unroll
        for (int ii = 0; ii < 2; ++ii) {
            int fi = tid + ii * 256; int r = fi >> 4, s4 = fi & 15;
            *(float4*)&pls[r][s4 * 4] =
                *(const float4*)&elog[(size_t)(t0 + r) * NSLOT + s4 * 4];
        }
        __syncthreads();
        for (int t = 0; t < 32; ++t) {
            float4 xv0 = *(const float4*)&xs[t][dg * 4];
            float4 xv1 = *(const float4*)&xs[t][128 + dg * 4];
            #pragma unroll
            for (int i = 0; i < 8; ++i) {
                float p = pls[t][sgq * 8 + i];
                acc0[i].x += p * xv0.x; acc0[i].y += p * xv0.y;
                acc0[i].z += p * xv0.z; acc0[i].w += p * xv0.w;
                acc1[i].x += p * xv1.x; acc1[i].y += p * xv1.y;
                acc1[i].z += p * xv1.z; acc1[i].w += p * xv1.w;
            }
        }
    }
    #pragma unroll
    for (int i = 0; i < 8; ++i) {
        int s = sgq * 8 + i;
        *(float4*)&partial[((size_t)blockIdx.y * NSLOT + s) * D_DIM + d0 + dg * 4] = acc0[i];
        *(float4*)&partial[((size_t)blockIdx.y * NSLOT + s) * D_DIM + d0 + 128 + dg * 4] = acc1[i];
    }
}

// ---------------------------------------------------------------------------
// Kernel 4: slot_in = (1/Z_s) * sum_c partial. grid 128, block 256.
// 8-deep explicit load batches for ILP; folds invZ from the 4 atomic bins.
// ---------------------------------------------------------------------------
__global__ __launch_bounds__(256) void k_sred(const float* __restrict__ partial,
                                              const float* __restrict__ pz4,
                                              float* __restrict__ slot_in) {
    const size_t idx = (size_t)blockIdx.x * 256 + threadIdx.x;   // float4 index
    const int s = (int)(idx >> 9);                               // 512 f4 per slot
    const float iz = 1.f / (pz4[s] + pz4[64 + s] + pz4[128 + s] + pz4[192 + s]);
    const float4* p4 = (const float4*)partial;
    float4 a = {0.f, 0.f, 0.f, 0.f};
    for (int c0 = 0; c0 < 8; ++c0) {
        float4 v[8];
        #pragma unroll
        for (int j = 0; j < 8; ++j)
            v[j] = p4[(size_t)(c0 * 8 + j) * (NSLOT * D_DIM / 4) + idx];
        #pragma unroll
        for (int j = 0; j < 8; ++j) {
            a.x += v[j].x; a.y += v[j].y; a.z += v[j].z; a.w += v[j].w;
        }
    }
    a.x *= iz; a.y *= iz; a.z *= iz; a.w *= iz;
    ((float4*)slot_in)[idx] = a;
}

// ---------------------------------------------------------------------------
// Kernel 5: h = gelu(W1 @ slot_in + b1). One wave per row, grid 16384.
// ---------------------------------------------------------------------------
__global__ __launch_bounds__(256) void k_mlp1(const float* __restrict__ W1,
                                              const float* __restrict__ b1,
                                              const float* __restrict__ slot_in,
                                              float* __restrict__ h) {
    const int wave = threadIdx.x >> 6, lane = threadIdx.x & 63;
    const int row = blockIdx.x * 4 + wave;           // e*1024 + j
    const int e = row >> 10;
    const float* wr = W1 + (size_t)row * D_DIM;
    const float* xr = slot_in + (size_t)e * D_DIM;
    float acc = 0.f;
    #pragma unroll
    for (int i = 0; i < 8; ++i) {
        int k = (lane + i * 64) * 4;
        float4 w4 = *(const float4*)(wr + k);
        float4 x4 = *(const float4*)(xr + k);
        acc += w4.x * x4.x + w4.y * x4.y + w4.z * x4.z + w4.w * x4.w;
    }
    #pragma unroll
    for (int off = 32; off; off >>= 1) acc += __shfl_xor(acc, off);
    if (lane == 0) {
        float v = acc + b1[row];
        h[row] = 0.5f * v * (1.f + erff(v * 0.70710678118654752f));
    }
}

// Kernel 6: slot_out = W2 @ h + b2. One wave per row, grid 32768.
__global__ __launch_bounds__(256) void k_mlp2(const float* __restrict__ W2,
                                              const float* __restrict__ b2,
                                              const float* __restrict__ h,
                                              float* __restrict__ slot_out) {
    const int wave = threadIdx.x >> 6, lane = threadIdx.x & 63;
    const int row = blockIdx.x * 4 + wave;           // e*2048 + d
    const int e = row >> 11;
    const float* wr = W2 + (size_t)row * H_DIM;
    const float* xr = h + (size_t)e * H_DIM;
    float acc = 0.f;
    #pragma unroll
    for (int i = 0; i < 4; ++i) {
        int k = (lane + i * 64) * 4;
        float4 w4 = *(const float4*)(wr + k);
        float4 x4 = *(const float4*)(xr + k);
        acc += w4.x * x4.x + w4.y * x4.y + w4.z * x4.z + w4.w * x4.w;
    }
    #pragma unroll
    for (int off = 32; off; off >>= 1) acc += __shfl_xor(acc, off);
    if (lane == 0) slot_out[row] = acc + b2[row];
}

// ---------------------------------------------------------------------------
// Kernel 7: y[t] = (sum_s E[t][s]*so[s]) / (sum_s E[t][s]). Block 128x128.
// grid (16, 128) — d fast so concurrent blocks share the elog slice in L2.
// ---------------------------------------------------------------------------
__global__ __launch_bounds__(256) void k_combine(const float* __restrict__ elog,
                                                 const float* __restrict__ so,
                                                 float* __restrict__ y) {
    __shared__ float cl[128][68];
    __shared__ float sol[64][128];
    __shared__ float rinv[128];
    const int tid = threadIdx.x;
    const int d0 = blockIdx.x * 128;
    const int tb = blockIdx.y * 128;
    const int tq = tid >> 4;    // 0..15
    const int dgq = tid & 15;   // 0..15
    #pragma unroll
    for (int ii = 0; ii < 8; ++ii) {          // stage E: 128x64
        int fi = tid + ii * 256; int r = fi >> 4, s4 = fi & 15;
        *(float4*)&cl[r][s4 * 4] =
            *(const float4*)&elog[(size_t)(tb + r) * NSLOT + s4 * 4];
    }
    #pragma unroll
    for (int ii = 0; ii < 8; ++ii) {          // stage slot_out tile 64x128
        int fi = tid + ii * 256; int r = fi >> 5, c4 = fi & 31;
        *(float4*)&sol[r][c4 * 4] =
            *(const float4*)&so[(size_t)r * D_DIM + d0 + c4 * 4];
    }
    __syncthreads();
    if (tid < 128) {                          // row sums -> 1/Z_t
        float zs = 0.f;
        #pragma unroll
        for (int q = 0; q < 16; ++q) {
            float4 v = *(const float4*)&cl[tid][q * 4];
            zs += v.x + v.y + v.z + v.w;
        }
        rinv[tid] = 1.f / zs;
    }
    __syncthreads();
    float4 acc0[8] = {}, acc1[8] = {};
    for (int s = 0; s < 64; ++s) {
        float4 sv0 = *(const float4*)&sol[s][dgq * 4];
        float4 sv1 = *(const float4*)&sol[s][64 + dgq * 4];
        #pragma unroll
        for (int i = 0; i < 8; ++i) {
            float cv = cl[tq + 16 * i][s];
            acc0[i].x += cv * sv0.x; acc0[i].y += cv * sv0.y;
            acc0[i].z += cv * sv0.z; acc0[i].w += cv * sv0.w;
            acc1[i].x += cv * sv1.x; acc1[i].y += cv * sv1.y;
            acc1[i].z += cv * sv1.z; acc1[i].w += cv * sv1.w;
        }
    }
    #pragma unroll
    for (int i = 0; i < 8; ++i) {
        float rz = rinv[tq + 16 * i];
        acc0[i].x *= rz; acc0[i].y *= rz; acc0[i].z *= rz; acc0[i].w *= rz;
        acc1[i].x *= rz; acc1[i].y *= rz; acc1[i].z *= rz; acc1[i].w *= rz;
        *(float4*)&y[(size_t)(tb + tq + 16 * i) * D_DIM + d0 + dgq * 4] = acc0[i];
        *(float4*)&y[(size_t)(tb + tq + 16 * i) * D_DIM + d0 + 64 + dgq * 4] = acc1[i];
    }
}

// ---------------------------------------------------------------------------
extern "C" void kernel_launch(void* const* d_in, const int* in_sizes, int n_in,
                              void* d_out, int out_size, void* d_ws, size_t ws_size,
                              hipStream_t stream) {
    const float* x  = (const float*)d_in[0];
    const float* Wd = (const float*)d_in[1];
    const float* W1 = (const float*)d_in[2];
    const float* b1 = (const float*)d_in[3];
    const float* W2 = (const float*)d_in[4];
    const float* b2 = (const float*)d_in[5];
    float* y = (float*)d_out;

    float* w = (float*)d_ws;
    float* plog     = w;                                      // 8*16384*64
    float* elog     = plog + (size_t)KSPLIT * T_TOK * NSLOT;  // 16384*64
    float* pz4      = elog + (size_t)T_TOK * NSLOT;           // 256 bins
    float* partial  = pz4 + 256;                              // 64*64*2048
    float* slot_in  = partial + (size_t)64 * NSLOT * D_DIM;   // 64*2048
    float* h        = slot_in + (size_t)NSLOT * D_DIM;        // 64*1024
    float* slot_out = h + (size_t)NSLOT * H_DIM;              // 64*2048

    k_logits<<<dim3(T_TOK / TBLK, KSPLIT), 256, 0, stream>>>(x, Wd, plog, pz4);
    k_lsum<<<512, 256, 0, stream>>>(plog, elog, pz4);
    k_slot<<<dim3(8, 64), 256, 0, stream>>>(x, elog, partial);
    k_sred<<<128, 256, 0, stream>>>(partial, pz4, slot_in);
    k_mlp1<<<(NSLOT * H_DIM) / 4, 256, 0, stream>>>(W1, b1, slot_in, h);
    k_mlp2<<<(NSLOT * D_DIM) / 4, 256, 0, stream>>>(W2, b2, h, slot_out);
    k_combine<<<dim3(16, 128), 256, 0, stream>>>(elog, slot_out, y);
}